// Round 1
// baseline (325.979 us; speedup 1.0000x reference)
//
#include <hip/hip_runtime.h>

// ---------------------------------------------------------------------------
// DynamicHippocampus: 4-step spiking network.
// EC --PP--> DG --MF--> CA3 (--RC--> CA3) --SC--> CA1
// Izhikevich excitatory populations, scalar-collapsed LIF inhibition
// (LIF input is a broadcast mean -> whole population is one scalar).
// Spike bitmasks + per-(step,pop) "any spike" flags let transmit kernels
// early-exit when the source population is silent (data-dependent, general).
// ---------------------------------------------------------------------------

#define N_EC  100000
#define N_DG  400000
#define N_CA3 120000
#define N_CA1 100000

constexpr int PP_NNZ = 10000000, MF_NNZ = 8000000, RC_NNZ = 6000000, SC_NNZ = 6000000;
constexpr int T_STEPS = 4;

// ---- workspace layout (float offsets) ----
enum : size_t {
  OFF_EC_V = 0,
  OFF_EC_U = OFF_EC_V + N_EC,
  OFF_DG_V = OFF_EC_U + N_EC,
  OFF_DG_U = OFF_DG_V + N_DG,
  OFF_C3_V = OFF_DG_U + N_DG,
  OFF_C3_U = OFF_C3_V + N_CA3,
  OFF_C1_V = OFF_C3_U + N_CA3,
  OFF_C1_U = OFF_C1_V + N_CA1,
  OFF_DG_I = OFF_C1_U + N_CA1,
  OFF_C3_I = OFF_DG_I + N_DG,
  OFF_C1_I = OFF_C3_I + N_CA3,
  OFF_SCAL = OFF_C1_I + N_CA1,   // 64 floats: sums[12] @0; iv_dg[5]@16, iv_c3[5]@21, iv_c1[5]@26
  OFF_FLAG = OFF_SCAL + 64,      // 16 ints (as float slots)
  OFF_MASK = OFF_FLAG + 64,      // u64 bitmask region (float offset is even -> 8B aligned)
};
enum : size_t {  // u64-word offsets inside mask region
  MW_EC = 0,    MW_EC_N = 1600,
  MW_DG = 1600, MW_DG_N = 6272,
  MW_C3 = 7872, MW_C3_N = 1900,
  MW_TOT = 9772,
};

// ---------------------------------------------------------------------------
__global__ __launch_bounds__(256)
void init_kernel(float* __restrict__ ws) {
  int i0 = blockIdx.x * blockDim.x + threadIdx.x;
  int stride = gridDim.x * blockDim.x;
  int* flags = (int*)(ws + OFF_FLAG);
  unsigned long long* c3m = (unsigned long long*)(ws + OFF_MASK) + MW_C3;
  for (int j = i0; j < N_DG; j += stride) {
    ws[OFF_DG_V + j] = -65.0f; ws[OFF_DG_U + j] = -13.0f; ws[OFF_DG_I + j] = 0.0f;
    if (j < N_EC)  { ws[OFF_EC_V + j] = -65.0f; ws[OFF_EC_U + j] = -13.0f; }
    if (j < N_CA3) { ws[OFF_C3_V + j] = -65.0f; ws[OFF_C3_U + j] = -13.0f; ws[OFF_C3_I + j] = 0.0f; }
    if (j < N_CA1) { ws[OFF_C1_V + j] = -65.0f; ws[OFF_C1_U + j] = -13.0f; ws[OFF_C1_I + j] = 0.0f; }
    if (j < 64) ws[OFF_SCAL + j] = 0.0f;
    if (j < 16) flags[j] = 0;
    if (j < (int)MW_C3_N) c3m[j] = 0ull;
  }
}

// ---------------------------------------------------------------------------
// Sparse COO transmit: I[tgt] += val where spike bit of src is set.
// Early-exits (whole kernel) if the source population produced no spikes.
// Also accumulates the total injected current (== sum(I)) for the mean.
__global__ __launch_bounds__(256)
void transmit_kernel(const int* __restrict__ src, const int* __restrict__ tgt,
                     const float* __restrict__ val,
                     const unsigned long long* __restrict__ mask,
                     float* __restrict__ I, float* __restrict__ sum_slot,
                     const int* __restrict__ flag, int nnz4)
{
  if (*flag == 0) return;   // source population silent this step
  float local = 0.0f;
  const int stride = gridDim.x * blockDim.x;
  for (int i = blockIdx.x * blockDim.x + threadIdx.x; i < nnz4; i += stride) {
    const int4   s4 = reinterpret_cast<const int4*>(src)[i];
    const int4   t4 = reinterpret_cast<const int4*>(tgt)[i];
    const float4 v4 = reinterpret_cast<const float4*>(val)[i];
    const int   ss[4] = {s4.x, s4.y, s4.z, s4.w};
    const int   tt[4] = {t4.x, t4.y, t4.z, t4.w};
    const float vv[4] = {v4.x, v4.y, v4.z, v4.w};
#pragma unroll
    for (int k = 0; k < 4; ++k) {
      if ((mask[ss[k] >> 6] >> (ss[k] & 63)) & 1ull) {
        atomicAdd(&I[tt[k]], vv[k]);
        local += vv[k];
      }
    }
  }
  // block reduction -> single atomic per block
  for (int off = 32; off > 0; off >>= 1) local += __shfl_down(local, off);
  __shared__ float red[4];
  if ((threadIdx.x & 63) == 0) red[threadIdx.x >> 6] = local;
  __syncthreads();
  if (threadIdx.x == 0) {
    float bs = red[0] + red[1] + red[2] + red[3];
    if (bs != 0.0f) atomicAdd(sum_slot, bs);
  }
}

// ---------------------------------------------------------------------------
__device__ __forceinline__ void izh_step(float& vv, float& uu, float I,
                                         float c, float d, bool& s) {
  vv = vv + (0.04f * vv * vv + 5.0f * vv + 140.0f - uu + I) * 0.5f;  // DT=0.5
  vv = fminf(fmaxf(vv, -90.0f), 40.0f);
  uu = uu + 0.02f * (0.2f * vv - uu) * 0.5f;   // A=0.02, B=0.2, uses clamped v
  s = (vv >= 30.0f);
  if (s) { vv = c; uu = uu + d; }
}

// EC: driven by external current, no inhibition.
__global__ __launch_bounds__(256)
void izh_ec_kernel(float* __restrict__ v, float* __restrict__ u,
                   const float* __restrict__ c, const float* __restrict__ d,
                   const float* __restrict__ drive,
                   unsigned long long* __restrict__ mask,
                   int* __restrict__ flag, int n)
{
  int i = blockIdx.x * blockDim.x + threadIdx.x;
  bool s = false;
  if (i < n) {
    float vv = v[i], uu = u[i];
    izh_step(vv, uu, drive[i], c[i], d[i], s);
    v[i] = vv; u[i] = uu;
  }
  unsigned long long m = __ballot(s);
  if ((threadIdx.x & 63) == 0) {
    mask[i >> 6] = m;
    if (m) atomicOr(flag, 1);
  }
}

// DG/CA3/CA1: input from Ibuf minus scalar LIF inhibition; resets Ibuf for
// the next step; optionally emits spike mask / writes output (CA1 v).
__global__ __launch_bounds__(256)
void izh_lif_kernel(float* __restrict__ v, float* __restrict__ u,
                    const float* __restrict__ c, const float* __restrict__ d,
                    float* __restrict__ Ibuf,
                    const float* __restrict__ sum_slot,
                    const float* __restrict__ iv_prev, float* __restrict__ iv_next,
                    float inv_n,
                    unsigned long long* __restrict__ mask, int* __restrict__ flag,
                    float* __restrict__ out, int n)
{
  // scalar LIF population (uniform input == mean of Ibuf)
  float mean = (*sum_slot) * inv_n;
  float ivn  = 0.9f * (*iv_prev) + 0.1f * mean;   // TAU_I=0.9
  bool  lif_s = (ivn >= 1.0f);                    // THR_I=1.0
  float inh   = lif_s ? 2.0f : 0.0f;              // INH_GAIN * is.mean()
  if (blockIdx.x == 0 && threadIdx.x == 0) *iv_next = lif_s ? 0.0f : ivn;

  int i = blockIdx.x * blockDim.x + threadIdx.x;
  bool s = false;
  if (i < n) {
    float vv = v[i], uu = u[i];
    float I = Ibuf[i] - inh;
    Ibuf[i] = 0.0f;                  // ready for next step's scatter
    izh_step(vv, uu, I, c[i], d[i], s);
    v[i] = vv; u[i] = uu;
    if (out) out[i] = vv;
  }
  if (mask) {
    unsigned long long m = __ballot(s);
    if ((threadIdx.x & 63) == 0) {
      mask[i >> 6] = m;
      if (m) atomicOr(flag, 1);
    }
  }
}

// ---------------------------------------------------------------------------
extern "C" void kernel_launch(void* const* d_in, const int* in_sizes, int n_in,
                              void* d_out, int out_size, void* d_ws, size_t ws_size,
                              hipStream_t stream) {
  const float* drive  = (const float*)d_in[0];
  const int *pp_src = (const int*)d_in[1], *pp_tgt = (const int*)d_in[2];
  const float* pp_val = (const float*)d_in[3];
  const int *mf_src = (const int*)d_in[4], *mf_tgt = (const int*)d_in[5];
  const float* mf_val = (const float*)d_in[6];
  const int *rc_src = (const int*)d_in[7], *rc_tgt = (const int*)d_in[8];
  const float* rc_val = (const float*)d_in[9];
  const int *sc_src = (const int*)d_in[10], *sc_tgt = (const int*)d_in[11];
  const float* sc_val = (const float*)d_in[12];
  const float *ec_c = (const float*)d_in[13], *ec_d = (const float*)d_in[14];
  const float *dg_c = (const float*)d_in[15], *dg_d = (const float*)d_in[16];
  const float *c3_c = (const float*)d_in[17], *c3_d = (const float*)d_in[18];
  const float *c1_c = (const float*)d_in[19], *c1_d = (const float*)d_in[20];

  float* ws = (float*)d_ws;
  float* ec_v = ws + OFF_EC_V;  float* ec_u = ws + OFF_EC_U;
  float* dg_v = ws + OFF_DG_V;  float* dg_u = ws + OFF_DG_U;
  float* c3_v = ws + OFF_C3_V;  float* c3_u = ws + OFF_C3_U;
  float* c1_v = ws + OFF_C1_V;  float* c1_u = ws + OFF_C1_U;
  float* dg_I = ws + OFF_DG_I;  float* c3_I = ws + OFF_C3_I;  float* c1_I = ws + OFF_C1_I;
  float* scal = ws + OFF_SCAL;
  int*   flags = (int*)(ws + OFF_FLAG);
  unsigned long long* mbase = (unsigned long long*)(ws + OFF_MASK);
  unsigned long long* ec_m = mbase + MW_EC;
  unsigned long long* dg_m = mbase + MW_DG;
  unsigned long long* c3_m = mbase + MW_C3;

  float* out = (float*)d_out;
  auto grid = [](int n) { return (n + 255) / 256; };

  init_kernel<<<grid(N_DG), 256, 0, stream>>>(ws);

  for (int t = 0; t < T_STEPS; ++t) {
    float* sum_dg = &scal[t * 3 + 0];
    float* sum_c3 = &scal[t * 3 + 1];
    float* sum_c1 = &scal[t * 3 + 2];
    int* f_ec = &flags[t * 3 + 0];
    int* f_dg = &flags[t * 3 + 1];
    int* f_c3 = &flags[t * 3 + 2];
    int* f_c3_prev = (t == 0) ? &flags[15] : &flags[(t - 1) * 3 + 2]; // slot15 stays 0

    // EC update (external drive)
    izh_ec_kernel<<<grid(N_EC), 256, 0, stream>>>(
        ec_v, ec_u, ec_c, ec_d, drive + (size_t)t * N_EC, ec_m, f_ec, N_EC);
    // EC -> DG (perforant path)
    transmit_kernel<<<1024, 256, 0, stream>>>(
        pp_src, pp_tgt, pp_val, ec_m, dg_I, sum_dg, f_ec, PP_NNZ / 4);
    // DG update (+ scalar LIF inhibition)
    izh_lif_kernel<<<grid(N_DG), 256, 0, stream>>>(
        dg_v, dg_u, dg_c, dg_d, dg_I, sum_dg, &scal[16 + t], &scal[16 + t + 1],
        1.0f / (float)N_DG, dg_m, f_dg, nullptr, N_DG);
    // DG -> CA3 (mossy fibers) + CA3 -> CA3 recurrent (uses PREVIOUS c3 spikes)
    transmit_kernel<<<1024, 256, 0, stream>>>(
        mf_src, mf_tgt, mf_val, dg_m, c3_I, sum_c3, f_dg, MF_NNZ / 4);
    transmit_kernel<<<1024, 256, 0, stream>>>(
        rc_src, rc_tgt, rc_val, c3_m, c3_I, sum_c3, f_c3_prev, RC_NNZ / 4);
    // CA3 update (overwrites c3 spike mask AFTER recurrent transmit consumed it)
    izh_lif_kernel<<<grid(N_CA3), 256, 0, stream>>>(
        c3_v, c3_u, c3_c, c3_d, c3_I, sum_c3, &scal[21 + t], &scal[21 + t + 1],
        1.0f / (float)N_CA3, c3_m, f_c3, nullptr, N_CA3);
    // CA3 -> CA1 (Schaffer collaterals)
    transmit_kernel<<<1024, 256, 0, stream>>>(
        sc_src, sc_tgt, sc_val, c3_m, c1_I, sum_c1, f_c3, SC_NNZ / 4);
    // CA1 update; writes output v every step (last step's value persists)
    izh_lif_kernel<<<grid(N_CA1), 256, 0, stream>>>(
        c1_v, c1_u, c1_c, c1_d, c1_I, sum_c1, &scal[26 + t], &scal[26 + t + 1],
        1.0f / (float)N_CA1, nullptr, nullptr, out, N_CA1);
  }
}